// Round 1
// baseline (454.033 us; speedup 1.0000x reference)
//
#include <hip/hip_runtime.h>

// X: (16, 64, 256, 256) fp32, K: (3,3) fp32, same-shape output.
// Depthwise 3x3, stride 1, pad 1. HBM-bound: floor = 537 MB @ ~6.3 TB/s ~ 85-95 us.
// R1: 8-row register blocking + XCD-chunk block swizzle.        (450.7 us agg)
// R2: (a) halo via wave shuffles instead of scalar loads -> 1 VMEM instr/row
//         (lane i's left/right neighbors are lanes i-1/i+1's float4; wave
//          edges are exactly the image zero-pad since 64 lanes * 4 = 256 = W)
//     (b) 16-row stripes: read amp 1.25x -> 1.125x
//     (c) non-temporal float4 stores (output never re-read; keep L2 for halos)

#define CONV_H 256
#define CONV_W 256
#define CONV_W4 64                      // float4 groups per row == wave size
#define NPLANES (16 * 64)               // B*C independent planes
#define ROWS_PER_THREAD 16
#define STRIPES (CONV_H / ROWS_PER_THREAD)   // 16 stripes per plane

typedef float v4f __attribute__((ext_vector_type(4)));

struct Row { float4 c; float l, r; };

__device__ __forceinline__ Row load_row(const float* __restrict__ rowp, int lane) {
    Row v;
    v.c = *(const float4*)rowp;                 // single coalesced 16B load
    float l = __shfl_up(v.c.w, 1);              // lane i-1's col3 == my col-1
    float r = __shfl_down(v.c.x, 1);            // lane i+1's col0 == my col+4
    v.l = (lane == 0)  ? 0.f : l;               // col 0 left pad
    v.r = (lane == 63) ? 0.f : r;               // col 255 right pad
    return v;
}

__device__ __forceinline__ Row zero_row() {
    Row v;
    v.c = make_float4(0.f, 0.f, 0.f, 0.f);
    v.l = 0.f; v.r = 0.f;
    return v;
}

__global__ __launch_bounds__(256)
void conv3x3_kernel(const float* __restrict__ X,
                    const float* __restrict__ Kw,
                    float* __restrict__ out)
{
    const float k00 = Kw[0], k01 = Kw[1], k02 = Kw[2];
    const float k10 = Kw[3], k11 = Kw[4], k12 = Kw[5];
    const float k20 = Kw[6], k21 = Kw[7], k22 = Kw[8];

    // XCD swizzle: blocks b with b%8==x run on XCD x; remap so each XCD owns
    // a contiguous 1/8 chunk of logical block space (vertically adjacent
    // stripes share boundary rows in the same XCD's L2).
    const int chunk = gridDim.x >> 3;                       // 512
    const int lb = (blockIdx.x & 7) * chunk + (blockIdx.x >> 3);

    const int tid    = lb * blockDim.x + threadIdx.x;
    const int lane   = threadIdx.x & 63;                    // == w4 (64*4 == W)
    const int w4     = tid & (CONV_W4 - 1);                 // lane-contiguous -> coalesced
    const int stripe = tid >> 6;                            // 16-row stripe id
    const int h0     = (stripe & (STRIPES - 1)) << 4;       // 0,16,...,240
    const int p      = stripe >> 4;                         // plane

    const float* plane = X + (size_t)p * (CONV_H * CONV_W);
    const int col0 = w4 << 2;
    float* outp = out + (size_t)p * (CONV_H * CONV_W) + (size_t)h0 * CONV_W + col0;

    // rolling window: rm = row h-1, rc = row h, rp = row h+1
    Row rm = (h0 > 0) ? load_row(plane + (h0 - 1) * CONV_W + col0, lane) : zero_row();
    Row rc = load_row(plane + h0 * CONV_W + col0, lane);

    #pragma unroll
    for (int i = 0; i < ROWS_PER_THREAD; ++i) {
        const int hp = h0 + i + 1;                          // wave-uniform cond
        Row rp = (hp < CONV_H) ? load_row(plane + hp * CONV_W + col0, lane)
                               : zero_row();

        float4 o;
        o.x = k00 * rm.l   + k01 * rm.c.x + k02 * rm.c.y
            + k10 * rc.l   + k11 * rc.c.x + k12 * rc.c.y
            + k20 * rp.l   + k21 * rp.c.x + k22 * rp.c.y;
        o.y = k00 * rm.c.x + k01 * rm.c.y + k02 * rm.c.z
            + k10 * rc.c.x + k11 * rc.c.y + k12 * rc.c.z
            + k20 * rp.c.x + k21 * rp.c.y + k22 * rp.c.z;
        o.z = k00 * rm.c.y + k01 * rm.c.z + k02 * rm.c.w
            + k10 * rc.c.y + k11 * rc.c.z + k12 * rc.c.w
            + k20 * rp.c.y + k21 * rp.c.z + k22 * rp.c.w;
        o.w = k00 * rm.c.z + k01 * rm.c.w + k02 * rm.r
            + k10 * rc.c.z + k11 * rc.c.w + k12 * rc.r
            + k20 * rp.c.z + k21 * rp.c.w + k22 * rp.r;

        v4f ov = { o.x, o.y, o.z, o.w };
        __builtin_nontemporal_store(ov, (v4f*)(outp + i * CONV_W));

        rm = rc;
        rc = rp;
    }
}

extern "C" void kernel_launch(void* const* d_in, const int* in_sizes, int n_in,
                              void* d_out, int out_size, void* d_ws, size_t ws_size,
                              hipStream_t stream) {
    const float* X  = (const float*)d_in[0];
    const float* Kw = (const float*)d_in[1];
    float* out = (float*)d_out;

    // one thread per (16 rows x 4 cols): 1024 planes * 16 stripes * 64 lanes
    const int total_threads = NPLANES * STRIPES * CONV_W4;   // 1,048,576
    const int block = 256;
    const int grid = total_threads / block;                  // 4096 (div by 8)
    conv3x3_kernel<<<grid, block, 0, stream>>>(X, Kw, out);
}

// Round 2
// 442.744 us; speedup vs baseline: 1.0255x; 1.0255x over previous
//
#include <hip/hip_runtime.h>

// X: (16, 64, 256, 256) fp32, K: (3,3) fp32, same-shape output.
// Depthwise 3x3, stride 1, pad 1. HBM-bound floor ~90 us; L3 holds ~half of X
// so true floor is lower. R2 measured 164.5 us/dispatch @ 2.54 TB/s, VALU 8.7%
// -> latency-bound, NOT BW-bound.
// R3: (a) UNCONDITIONAL clamped row loads (the per-iteration `hp<H ? load :
//         zero` branch forced conservative s_waitcnt vmcnt(0) every row,
//         collapsing MLP to ~1); out-of-range rows zeroed branchlessly AFTER
//         the load via mask multiply.
//     (b) explicit 4-deep raw-row prefetch pipeline (static slot indices via
//         full unroll) -> ~3 loads in flight per wave, counted vmcnt waits.
//     (c) back to 8 rows/thread: 32768 waves (4 per wave-slot) for wave-level
//         MLP; 1.25x read amp is irrelevant at 40% of BW.

#define CONV_H 256
#define CONV_W 256
#define CONV_W4 64                      // float4 groups per row == wave size
#define NPLANES (16 * 64)               // B*C independent planes
#define ROWS_PER_THREAD 8
#define STRIPES (CONV_H / ROWS_PER_THREAD)   // 32 stripes per plane
#define PDEPTH 4                        // prefetch pipeline depth (pow2)

typedef float v4f __attribute__((ext_vector_type(4)));

struct Row { float4 c; float l, r; };

// Expand a raw float4 row into center + halo via wave shuffles.
// `valid` is 1.0 for in-range rows, 0.0 for zero-pad rows (branchless).
__device__ __forceinline__ Row expand_row(float4 c, int lane, float valid) {
    Row v;
    float l = __shfl_up(c.w, 1);                // lane i-1's col3 == my col-1
    float r = __shfl_down(c.x, 1);              // lane i+1's col0 == my col+4
    v.c.x = c.x * valid;
    v.c.y = c.y * valid;
    v.c.z = c.z * valid;
    v.c.w = c.w * valid;
    v.l = (lane == 0)  ? 0.f : l * valid;       // col 0 left pad
    v.r = (lane == 63) ? 0.f : r * valid;       // col 255 right pad
    return v;
}

__global__ __launch_bounds__(256)
void conv3x3_kernel(const float* __restrict__ X,
                    const float* __restrict__ Kw,
                    float* __restrict__ out)
{
    const float k00 = Kw[0], k01 = Kw[1], k02 = Kw[2];
    const float k10 = Kw[3], k11 = Kw[4], k12 = Kw[5];
    const float k20 = Kw[6], k21 = Kw[7], k22 = Kw[8];

    // XCD swizzle: physical blocks b with b%8==x run on XCD x; remap so each
    // XCD owns a contiguous 1/8 chunk of logical block space.
    const int chunk = gridDim.x >> 3;                       // 1024
    const int lb = (blockIdx.x & 7) * chunk + (blockIdx.x >> 3);

    const int tid    = lb * blockDim.x + threadIdx.x;
    const int lane   = threadIdx.x & 63;                    // == w4 (64*4 == W)
    const int w4     = tid & (CONV_W4 - 1);                 // lane-contiguous
    const int stripe = tid >> 6;                            // 8-row stripe id
    const int h0     = (stripe & (STRIPES - 1)) << 3;       // 0,8,...,248
    const int p      = stripe >> 5;                         // plane

    const float* colp = X + (size_t)p * (CONV_H * CONV_W) + (w4 << 2);
    float* outp = out + (size_t)p * (CONV_H * CONV_W)
                      + (size_t)h0 * CONV_W + (w4 << 2);

    // --- prologue: issue PDEPTH unconditional loads (rows h0-1 .. h0+2) ---
    float4 raw[PDEPTH];
    #pragma unroll
    for (int j = 0; j < PDEPTH; ++j) {
        int r   = h0 - 1 + j;
        int rcl = min(max(r, 0), CONV_H - 1);               // clamp, no branch
        raw[j] = *(const float4*)(colp + rcl * CONV_W);
    }

    Row rm = expand_row(raw[0], lane, (h0 > 0) ? 1.f : 0.f);
    Row rc = expand_row(raw[1], lane, 1.f);

    #pragma unroll
    for (int i = 0; i < ROWS_PER_THREAD; ++i) {
        // prefetch row h0+3+i into slot i%4 (its old row h0-1+i is dead:
        // it was expanded into registers two iterations ago)
        if (i < ROWS_PER_THREAD - 2) {                      // compile-time
            int r   = h0 + PDEPTH - 1 + i;
            int rcl = min(r, CONV_H - 1);
            raw[i & (PDEPTH - 1)] = *(const float4*)(colp + rcl * CONV_W);
        }

        // consume row h0+1+i from slot (i+2)%4; only the last stripe's last
        // row (256) is out of range -> branchless zero mask
        const int rpr = h0 + 1 + i;
        Row rp = expand_row(raw[(i + 2) & (PDEPTH - 1)], lane,
                            (rpr < CONV_H) ? 1.f : 0.f);

        float4 o;
        o.x = k00 * rm.l   + k01 * rm.c.x + k02 * rm.c.y
            + k10 * rc.l   + k11 * rc.c.x + k12 * rc.c.y
            + k20 * rp.l   + k21 * rp.c.x + k22 * rp.c.y;
        o.y = k00 * rm.c.x + k01 * rm.c.y + k02 * rm.c.z
            + k10 * rc.c.x + k11 * rc.c.y + k12 * rc.c.z
            + k20 * rp.c.x + k21 * rp.c.y + k22 * rp.c.z;
        o.z = k00 * rm.c.y + k01 * rm.c.z + k02 * rm.c.w
            + k10 * rc.c.y + k11 * rc.c.z + k12 * rc.c.w
            + k20 * rp.c.y + k21 * rp.c.z + k22 * rp.c.w;
        o.w = k00 * rm.c.z + k01 * rm.c.w + k02 * rm.r
            + k10 * rc.c.z + k11 * rc.c.w + k12 * rc.r
            + k20 * rp.c.z + k21 * rp.c.w + k22 * rp.r;

        v4f ov = { o.x, o.y, o.z, o.w };
        __builtin_nontemporal_store(ov, (v4f*)(outp + i * CONV_W));

        rm = rc;
        rc = rp;
    }
}

extern "C" void kernel_launch(void* const* d_in, const int* in_sizes, int n_in,
                              void* d_out, int out_size, void* d_ws, size_t ws_size,
                              hipStream_t stream) {
    const float* X  = (const float*)d_in[0];
    const float* Kw = (const float*)d_in[1];
    float* out = (float*)d_out;

    // one thread per (8 rows x 4 cols): 1024 planes * 32 stripes * 64 lanes
    const int total_threads = NPLANES * STRIPES * CONV_W4;   // 2,097,152
    const int block = 256;
    const int grid = total_threads / block;                  // 8192 (div by 8)
    conv3x3_kernel<<<grid, block, 0, stream>>>(X, Kw, out);
}